// Round 3
// baseline (1736.485 us; speedup 1.0000x reference)
//
#include <hip/hip_runtime.h>
#include <math.h>

typedef __attribute__((ext_vector_type(4))) float f32x4;
typedef __attribute__((ext_vector_type(8))) short bf16x8;

__device__ inline short f2bf(float f) {
    union { float f; unsigned u; } v; v.f = f;
    unsigned u = v.u;
    u += 0x7fffu + ((u >> 16) & 1u);   // RNE
    return (short)(u >> 16);
}

struct Params {
    const float *x, *weight, *Wqkv, *Wo, *ln1_g, *ln1_b, *ln2_g, *ln2_b,
                *fc1_w, *fc1_b, *fc2_w, *fc2_b;
    float *ws, *out;
    unsigned *bar;
};

#define NBLK 512u

// ---- grid barrier: monotonic counter, explicit agent-scope fences (G16) ----
__device__ inline void gsync(unsigned* bar, unsigned target) {
    __syncthreads();
    if (threadIdx.x == 0) {
        __threadfence();   // release: publish this block's writes device-wide
        __hip_atomic_fetch_add(bar, 1u, __ATOMIC_RELAXED, __HIP_MEMORY_SCOPE_AGENT);
        while (__hip_atomic_load(bar, __ATOMIC_RELAXED, __HIP_MEMORY_SCOPE_AGENT) < target)
            __builtin_amdgcn_s_sleep(1);
        __threadfence();   // acquire: invalidate so we see other blocks' writes
    }
    __syncthreads();
}

// ---- atomic split-K GEMM phase: out[32][N] += act[32][K] @ W[N][K]^T ----
__device__ inline void gemm_tasks(const float* __restrict__ W, const float* __restrict__ act,
                                  float* __restrict__ out, int N, int K,
                                  short lAs[32][136], int bid, int t) {
    int nbx = N >> 6;
    int ntask = nbx * (K >> 7);
    int lane = t & 63, wv = t >> 6, m = lane & 15, q = lane >> 4;
    int arow = t >> 3, acol = (t & 7) * 16;
    for (int task = bid; task < ntask; task += NBLK) {
        int bx = task % nbx, by = task / nbx;
        size_t kbeg = (size_t)by << 7;
        int nb = bx * 64 + wv * 16;
        const float* ap = act + (size_t)arow * K + kbeg + acol;
        float4 a0 = *(const float4*)(ap);
        float4 a1 = *(const float4*)(ap + 4);
        float4 a2 = *(const float4*)(ap + 8);
        float4 a3 = *(const float4*)(ap + 12);
        const float* B = W + (size_t)(nb + m) * K + kbeg + q * 8;
        float4 Bb[8];
        #pragma unroll
        for (int s = 0; s < 4; ++s) {
            Bb[2 * s]     = *(const float4*)(B + s * 32);
            Bb[2 * s + 1] = *(const float4*)(B + s * 32 + 4);
        }
        __syncthreads();   // previous task's lAs readers are done
        {
            short4 c0 = { f2bf(a0.x), f2bf(a0.y), f2bf(a0.z), f2bf(a0.w) };
            short4 c1 = { f2bf(a1.x), f2bf(a1.y), f2bf(a1.z), f2bf(a1.w) };
            short4 c2 = { f2bf(a2.x), f2bf(a2.y), f2bf(a2.z), f2bf(a2.w) };
            short4 c3 = { f2bf(a3.x), f2bf(a3.y), f2bf(a3.z), f2bf(a3.w) };
            *(short4*)&lAs[arow][acol]      = c0;
            *(short4*)&lAs[arow][acol + 4]  = c1;
            *(short4*)&lAs[arow][acol + 8]  = c2;
            *(short4*)&lAs[arow][acol + 12] = c3;
        }
        __syncthreads();
        f32x4 acc0 = {0.f, 0.f, 0.f, 0.f};
        f32x4 acc1 = {0.f, 0.f, 0.f, 0.f};
        #pragma unroll
        for (int s = 0; s < 4; ++s) {
            bf16x8 fa0 = *(const bf16x8*)&lAs[m][s * 32 + q * 8];
            bf16x8 fa1 = *(const bf16x8*)&lAs[m + 16][s * 32 + q * 8];
            float4 bl = Bb[2 * s], bh = Bb[2 * s + 1];
            bf16x8 fb = { f2bf(bl.x), f2bf(bl.y), f2bf(bl.z), f2bf(bl.w),
                          f2bf(bh.x), f2bf(bh.y), f2bf(bh.z), f2bf(bh.w) };
            acc0 = __builtin_amdgcn_mfma_f32_16x16x32_bf16(fa0, fb, acc0, 0, 0, 0);
            acc1 = __builtin_amdgcn_mfma_f32_16x16x32_bf16(fa1, fb, acc1, 0, 0, 0);
        }
        // C/D: col = lane&15 (feature nb+m), row = q*4+reg (token)
        float* op = out + (size_t)(q * 4) * N + nb + m;
        #pragma unroll
        for (int r = 0; r < 4; ++r) {
            atomicAdd(op + (size_t)r * N, acc0[r]);
            atomicAdd(op + (size_t)(r + 16) * N, acc1[r]);
        }
    }
}

// ---- LN row task.  outB!=null (prep1): outA=LN(v), outB=v.  outB==null (prep2): outA=LN(v)+v ----
__device__ inline void ln_task(const float* __restrict__ row,
                               const float* __restrict__ g, const float* __restrict__ b,
                               float* __restrict__ outA, float* __restrict__ outB,
                               float* red, int t) {
    float v[8];
    #pragma unroll
    for (int j = 0; j < 8; ++j) v[j] = row[j * 256 + t];
    float sm = 0.f, ss = 0.f;
    #pragma unroll
    for (int j = 0; j < 8; ++j) { sm += v[j]; ss += v[j] * v[j]; }
    for (int off = 32; off; off >>= 1) { sm += __shfl_xor(sm, off, 64); ss += __shfl_xor(ss, off, 64); }
    int wv = t >> 6, lane = t & 63;
    if (lane == 0) { red[wv] = sm; red[4 + wv] = ss; }
    __syncthreads();
    sm = red[0] + red[1] + red[2] + red[3];
    ss = red[4] + red[5] + red[6] + red[7];
    float mu = sm * (1.0f / 2048.0f);
    float rstd = rsqrtf(ss * (1.0f / 2048.0f) - mu * mu + 1e-5f);
    #pragma unroll
    for (int j = 0; j < 8; ++j) {
        int col = j * 256 + t;
        float lnv = (v[j] - mu) * rstd * g[col] + b[col];
        if (outB) { outA[col] = lnv; outB[col] = v[j]; }
        else      { outA[col] = lnv + v[j]; }
    }
}

__device__ inline void zero_task(float* __restrict__ p, int t) {   // zero 8192 floats
    float4 z = {0.f, 0.f, 0.f, 0.f};
    float4* p4 = (float4*)p;
    #pragma unroll
    for (int k = 0; k < 8; ++k) p4[k * 256 + t] = z;
}

__global__ __launch_bounds__(256, 2) void k_mega(Params P) {
    __shared__ short lAs[32][136];
    __shared__ float red[8];
    __shared__ float rsa[32];
    int bid = blockIdx.x, t = threadIdx.x;
    unsigned ph = 0;

    float* altx = P.ws;                  // 65536
    float* sbuf = P.ws + 65536;          // 65536
    float* y    = P.ws + 131072;         // 65536
    float* s2   = P.ws + 196608;         // 65536
    float* imv  = P.ws + 262144;         // 65536
    float* qkv  = P.ws + 327680;         // 196608
    float* h    = P.ws + 524288;         // 262144

    // ---------- phase 0: avgpool + sinusoidal bias into sbuf ----------
    {
        int wv = t >> 6, lane = t & 63;
        int p = bid * 4 + wv;            // 0..2047
        const float* row = P.x + (size_t)p * 2048;
        int c2 = p >> 6, c1 = p & 63;
        int m = c1 * 32 + c2;
        for (int seg = 0; seg < 32; ++seg) {
            float v = row[seg * 64 + lane];
            for (int off = 32; off; off >>= 1) v += __shfl_xor(v, off, 64);
            if (lane == 0) altx[seg * 2048 + m] = v * (1.0f / 64.0f);
        }
        if (bid < 32) {
            const float kln = logf(10000.0f) / 1024.0f;
            for (int l = t; l < 2048; l += 256) {
                int c = l & ~1;
                float ang = (float)bid * expf(-(float)c * kln);
                sbuf[bid * 2048 + l] = (l & 1) ? cosf(ang) : sinf(ang);
            }
        }
    }
    gsync(P.bar, ++ph * NBLK);
    // ---------- s = bias + weight @ altx ----------
    gemm_tasks(P.weight, altx, sbuf, 2048, 2048, lAs, bid, t);

    for (int a = 0; a < 3; ++a) {
        gsync(P.bar, ++ph * NBLK);
        // prep1: y = LN1(s), s2 = s; zero qkv
        if (bid < 32)      ln_task(sbuf + bid * 2048, P.ln1_g, P.ln1_b,
                                   y + bid * 2048, s2 + bid * 2048, red, t);
        else if (bid < 56) zero_task(qkv + (size_t)(bid - 32) * 8192, t);
        gsync(P.bar, ++ph * NBLK);
        gemm_tasks(P.Wqkv + (size_t)a * 12582912, y, qkv, 6144, 2048, lAs, bid, t);
        gsync(P.bar, ++ph * NBLK);
        // scan: per-head scalar attn + serial cumsum
        if (bid < 16) {
            int hh = bid;
            int i = t >> 3, sub = t & 7;
            const float* qr = qkv + (size_t)i * 6144 + hh * 128 + sub * 16;
            const float* kr = qr + 2048;
            float acc = 0.f;
            #pragma unroll
            for (int dd = 0; dd < 16; ++dd) acc += qr[dd] * kr[dd];
            acc += __shfl_xor(acc, 1, 64);
            acc += __shfl_xor(acc, 2, 64);
            acc += __shfl_xor(acc, 4, 64);
            if (sub == 0) rsa[i] = acc * 0.08838834764831845f;   // 1/sqrt(128)
            __syncthreads();
            if (t < 128) {
                float vs[32];
                #pragma unroll
                for (int i2 = 0; i2 < 32; ++i2)
                    vs[i2] = qkv[(size_t)i2 * 6144 + 4096 + hh * 128 + t];
                float a2 = 0.f;
                #pragma unroll
                for (int i2 = 0; i2 < 32; ++i2) {
                    a2 += rsa[i2] * vs[i2];
                    imv[i2 * 2048 + hh * 128 + t] = a2;
                }
            }
        }
        gsync(P.bar, ++ph * NBLK);
        gemm_tasks(P.Wo + (size_t)a * 4194304, imv, s2, 2048, 2048, lAs, bid, t);
        gsync(P.bar, ++ph * NBLK);
        // prep2: s = LN2(s2)+s2 into sbuf; zero h
        if (bid < 32)      ln_task(s2 + bid * 2048, P.ln2_g, P.ln2_b,
                                   sbuf + bid * 2048, nullptr, red, t);
        else if (bid < 64) zero_task(h + (size_t)(bid - 32) * 8192, t);
        gsync(P.bar, ++ph * NBLK);
        gemm_tasks(P.fc1_w, sbuf, h, 8192, 2048, lAs, bid, t);
        gsync(P.bar, ++ph * NBLK);
        // act: h = gelu(h + fc1_b); sout = broadcast(fc2_b)
        float* sout = (a == 2) ? P.out : sbuf;
        if (bid < 128) {
            size_t base = ((size_t)bid * 256 + t) * 8;
            #pragma unroll
            for (int j = 0; j < 8; ++j) {
                size_t idx = base + j;
                float v = h[idx] + P.fc1_b[idx & 8191];
                h[idx] = 0.5f * v * (1.0f + erff(v * 0.70710678118654752f));
            }
        } else if (bid < 160) {
            size_t base = ((size_t)(bid - 128) * 256 + t) * 8;
            #pragma unroll
            for (int j = 0; j < 8; ++j) {
                size_t idx = base + j;
                sout[idx] = P.fc2_b[idx & 2047];
            }
        }
        gsync(P.bar, ++ph * NBLK);
        gemm_tasks(P.fc2_w, h, sout, 2048, 8192, lAs, bid, t);
    }
}

extern "C" void kernel_launch(void* const* d_in, const int* in_sizes, int n_in,
                              void* d_out, int out_size, void* d_ws, size_t ws_size,
                              hipStream_t stream) {
    Params P;
    P.x      = (const float*)d_in[0];
    P.weight = (const float*)d_in[1];
    P.Wqkv   = (const float*)d_in[2];
    P.Wo     = (const float*)d_in[3];
    P.ln1_g  = (const float*)d_in[4];
    P.ln1_b  = (const float*)d_in[5];
    P.ln2_g  = (const float*)d_in[6];
    P.ln2_b  = (const float*)d_in[7];
    P.fc1_w  = (const float*)d_in[8];
    P.fc1_b  = (const float*)d_in[9];
    P.fc2_w  = (const float*)d_in[10];
    P.fc2_b  = (const float*)d_in[11];
    P.ws     = (float*)d_ws;
    P.out    = (float*)d_out;
    P.bar    = (unsigned*)((float*)d_ws + (1 << 20));   // 4 MB in, far from data
    hipMemsetAsync(P.bar, 0, 64, stream);               // graph-capturable reset
    k_mega<<<NBLK, 256, 0, stream>>>(P);
}